// Round 12
// baseline (210.277 us; speedup 1.0000x reference)
//
#include <hip/hip_runtime.h>
#include <hip/hip_bf16.h>

#define BB 2
#define SS 2048
#define DD 1024
#define HH 16
#define HD 64

typedef __attribute__((ext_vector_type(8))) short bf16x8;
typedef __attribute__((ext_vector_type(4))) float floatx4;

__device__ __forceinline__ short f2bf(float x) {
  __hip_bfloat16 h = __float2bfloat16(x);
  return __builtin_bit_cast(short, h);
}

// pack two fp32 -> two bf16 (RNE) in one instruction
__device__ __forceinline__ unsigned cvtpk_bf16(float lo, float hi) {
  unsigned r;
  asm("v_cvt_pk_bf16_f32 %0, %1, %2" : "=v"(r) : "v"(lo), "v"(hi));
  return r;
}

// async global->LDS, 16B per lane; LDS dest is wave-uniform base + lane*16
__device__ __forceinline__ void load_lds16(const void* g, void* l) {
  __builtin_amdgcn_global_load_lds(
      (const __attribute__((address_space(1))) unsigned int*)g,
      (__attribute__((address_space(3))) unsigned int*)l, 16, 0, 0);
}

__device__ __forceinline__ float redsum16(float v) {
  v += __shfl_xor(v, 1, 64);
  v += __shfl_xor(v, 2, 64);
  v += __shfl_xor(v, 4, 64);
  v += __shfl_xor(v, 8, 64);
  return v;
}

// ---------------------------------------------------------------------------
// prep: fused conv_in (q,k,v fp32->bf16, ROUND-12: 8 elems/thread — 2x
// float4 load + one int4 store, G13 sweet spot both sides; convert grid
// halves 12288->6144) + conv_w (Wq/Wk/Wv transpose) + conv_wo (Wo
// transpose). 1D grid 7168, block 256.
// ---------------------------------------------------------------------------
__global__ __launch_bounds__(256) void prep(
    const float* __restrict__ q, const float* __restrict__ k,
    const float* __restrict__ v, const float* __restrict__ Wq,
    const float* __restrict__ Wk, const float* __restrict__ Wv,
    const float* __restrict__ Wo, short* __restrict__ qo,
    short* __restrict__ ko, short* __restrict__ vo, short* __restrict__ qT,
    short* __restrict__ kT, short* __restrict__ vT, short* __restrict__ WoT) {
  __shared__ short sT[64 * 72];
  const int blk = blockIdx.x;
  if (blk < 6144) {
    const int which = blk >> 11, x = blk & 2047;
    const float* src = which == 0 ? q : which == 1 ? k : v;
    short* dst       = which == 0 ? qo : which == 1 ? ko : vo;
    size_t i = ((size_t)x * 256 + threadIdx.x) * 8;
    float4 f0 = *(const float4*)(src + i);
    float4 f1 = *(const float4*)(src + i + 4);
    alignas(16) short s[8];
    s[0] = f2bf(f0.x); s[1] = f2bf(f0.y); s[2] = f2bf(f0.z);
    s[3] = f2bf(f0.w); s[4] = f2bf(f1.x); s[5] = f2bf(f1.y);
    s[6] = f2bf(f1.z); s[7] = f2bf(f1.w);
    *(int4*)(dst + i) = *(const int4*)(s);
    return;
  }
  const int t = threadIdx.x, r = t >> 2, c0 = (t & 3) * 16;
  const float* src;
  short* dst;
  if (blk < 6912) {  // conv_w: W[h][1024][64] -> WT[h*64+e][1024]
    const int b2 = blk - 6144, which = b2 >> 8, rr = b2 & 255;
    const int dtile = rr & 15, h = rr >> 4, d0 = dtile * 64;
    const float* W = which == 0 ? Wq : which == 1 ? Wk : Wv;
    short* WT      = which == 0 ? qT : which == 1 ? kT : vT;
    src = W + ((size_t)h * DD + d0 + r) * HD + c0;
    dst = WT + ((size_t)h * HD + r) * DD + d0 + c0;
  } else {  // conv_wo: Wo[1024][1024] -> WoT[n][k]
    const int b3 = blk - 6912;
    const int k0 = (b3 & 15) * 64, n0 = (b3 >> 4) * 64;
    src = Wo + (size_t)(k0 + r) * DD + n0 + c0;
    dst = WoT + (size_t)(n0 + r) * DD + k0 + c0;
  }
  const float4* s4 = (const float4*)src;
  float4 f0 = s4[0], f1 = s4[1], f2 = s4[2], f3 = s4[3];
  const float ff[16] = {f0.x, f0.y, f0.z, f0.w, f1.x, f1.y, f1.z, f1.w,
                        f2.x, f2.y, f2.z, f2.w, f3.x, f3.y, f3.z, f3.w};
#pragma unroll
  for (int j = 0; j < 16; ++j) sT[r * 72 + c0 + j] = f2bf(ff[j]);
  __syncthreads();
  alignas(16) short tmp[16];
#pragma unroll
  for (int j = 0; j < 16; ++j) tmp[j] = sT[(c0 + j) * 72 + r];
  *(int4*)(dst) = *(const int4*)(tmp);
  *(int4*)(dst + 8) = *(const int4*)(tmp + 8);
}

// ---------------------------------------------------------------------------
// Projection GEMM: ph = x @ W, M=4096, N=1024, K=1024. Round-8-verified
// (measured 40.6/40.4us twice): i-fast decode, XOR slot-swizzle both sides
// (bank-conflict-free, 3.2M->65K), T4 counted-vmcnt triple-buffer pipeline
// (vmcnt(4) steady, vmcnt(0) last; stage k+2 after barrier). UNCHANGED.
// LDS 48KB (3 bufs) + aliased v-transpose tr; grid 768 = 3 blocks/CU.
// q/k: masked rows ZEROED (score 0 -> exp2(0)=1 in attn), q scaled
// 1/8*log2(e). v: fused transpose -> vhT[bh][e][s]. XCD-decoded.
// ---------------------------------------------------------------------------
__global__ __launch_bounds__(256) void proj(
    const short* __restrict__ xq, const short* __restrict__ xk,
    const short* __restrict__ xv, const short* __restrict__ WqT,
    const short* __restrict__ WkT, const short* __restrict__ WvT,
    const int* __restrict__ mask, short* __restrict__ qh,
    short* __restrict__ kh, short* __restrict__ vhT) {
  __shared__ union {
    struct {
      short A[3][128 * 32];  // K-loop staging, triple-buffered
      short B[3][128 * 32];
    } s;
    short tr[64 * 136];  // v-transpose half-tile staging (aliases, post-loop)
  } u;
  const int xcd = blockIdx.x & 7, tt = blockIdx.x >> 3;
  const int which = tt >> 5;              // 0..2
  const int rest = tt & 31;
  const int j = ((xcd & 3) << 1) | (rest >> 4);   // n-block 0..7
  const int i = ((xcd >> 2) << 4) | (rest & 15);  // m-block 0..31 (fast)
  const short* X  = which == 0 ? xq : which == 1 ? xk : xv;
  const short* WT = which == 0 ? WqT : which == 1 ? WkT : WvT;
  const int m0 = i * 128, n0 = j * 128;
  const int tid = threadIdx.x, wid = tid >> 6, lane = tid & 63;
  const int quad = lane >> 4, l16 = lane & 15;
  const int wr = wid >> 1, wc = wid & 1;

  auto stage = [&](int buf, int kk) {
#pragma unroll
    for (int ii = 0; ii < 2; ++ii) {
      const int c = wid * 2 + ii;
      const int ci = c * 64 + lane;
      const int srow = ci >> 2;
      const int sslot = (ci & 3) ^ ((ci >> 3) & 3);  // pre-swizzled source
      load_lds16(X + (size_t)(m0 + srow) * DD + kk + sslot * 8,
                 &u.s.A[buf][c * 512]);
      load_lds16(WT + (size_t)(n0 + srow) * DD + kk + sslot * 8,
                 &u.s.B[buf][c * 512]);
    }
  };

  floatx4 acc[4][4] = {};
  const int qs = (quad ^ ((l16 >> 1) & 3)) * 8;  // swizzled read slot
  stage(0, 0);
  stage(1, 32);
  int b0 = 0, b1 = 1, b2 = 2;
  for (int k0 = 0; k0 < DD; k0 += 32) {
    if (k0 + 32 < DD)
      asm volatile("s_waitcnt vmcnt(4)" ::: "memory");
    else
      asm volatile("s_waitcnt vmcnt(0)" ::: "memory");
    __builtin_amdgcn_s_barrier();
    __builtin_amdgcn_sched_barrier(0);
    if (k0 + 64 < DD) stage(b2, k0 + 64);
    bf16x8 af[4], bfr[4];
#pragma unroll
    for (int mi = 0; mi < 4; ++mi)
      af[mi] =
          *(const bf16x8*)&u.s.A[b0][(wr * 64 + mi * 16 + l16) * 32 + qs];
#pragma unroll
    for (int ni = 0; ni < 4; ++ni)
      bfr[ni] =
          *(const bf16x8*)&u.s.B[b0][(wc * 64 + ni * 16 + l16) * 32 + qs];
#pragma unroll
    for (int mi = 0; mi < 4; ++mi)
#pragma unroll
      for (int ni = 0; ni < 4; ++ni)
        acc[mi][ni] = __builtin_amdgcn_mfma_f32_16x16x32_bf16(
            af[mi], bfr[ni], acc[mi][ni], 0, 0, 0);
    const int t = b0; b0 = b1; b1 = b2; b2 = t;  // rotate buffers
  }

  if (which != 2) {
    short* dst = which == 0 ? qh : kh;
    // q: fold 1/sqrt(64) AND log2(e) (attn uses exp2). k: unit scale.
    const float scale = (which == 0) ? 0.18033688f : 1.0f;
#pragma unroll
    for (int mi = 0; mi < 4; ++mi)
#pragma unroll
      for (int r2 = 0; r2 < 4; ++r2) {
        const int m = m0 + wr * 64 + mi * 16 + quad * 4 + r2;
        const float rs = mask[m] ? 0.f : scale;  // zero masked rows
#pragma unroll
        for (int ni = 0; ni < 4; ++ni) {
          const int n = n0 + wc * 64 + ni * 16 + l16;
          dst[(size_t)m * DD + n] = f2bf(acc[mi][ni][r2] * rs);
        }
      }
  } else {
    // v: transpose 128x128 tile -> vhT[bh][e][s], two 64-row halves through
    // u.tr (aliases staging buffers — sync: K-loop reads must all be done)
    __syncthreads();
    const int b = m0 >> 11;
#pragma unroll
    for (int p = 0; p < 2; ++p) {
      if (wc == p) {  // waves holding nl in [p*64, p*64+64)
#pragma unroll
        for (int mi = 0; mi < 4; ++mi)
#pragma unroll
          for (int ni = 0; ni < 4; ++ni)
#pragma unroll
            for (int r2 = 0; r2 < 4; ++r2) {
              const int ml = wr * 64 + mi * 16 + quad * 4 + r2;  // s-local
              const int nl = ni * 16 + l16;  // (h,e)-local within half
              u.tr[nl * 136 + ml] = f2bf(acc[mi][ni][r2]);
            }
      }
      __syncthreads();
      const int row = tid >> 2, part = tid & 3;  // row 0..63, 32-short parts
      const int gn = n0 + p * 64 + row;
      const int h = gn >> 6, e = gn & 63;
      short* dstp = vhT + ((size_t)(b * HH + h) * HD + e) * SS + (m0 & 2047) +
                    part * 32;
      const short* srcl = &u.tr[row * 136 + part * 32];
#pragma unroll
      for (int jj = 0; jj < 4; ++jj)
        *(int4*)(dstp + jj * 8) = *(const int4*)(srcl + jj * 8);
      if (p == 0) __syncthreads();
    }
  }
}

// ---------------------------------------------------------------------------
// Flash attention, cooperative-LDS version (round-6 body, passed 5 rounds).
// ROUND-12: CU LOAD-BALANCED iblk decode. All 128 blocks/XCD are co-resident
// (4/CU x 32 CU); breadth-first fill gives CU c slots {c, c+32, c+64, c+96}
// = g-values {g, g+8, g+16, g+24}. Old monotone decode -> per-CU tile sums
// 52..80 (worst CU = tail). New: g=slot>>2, j=g&7, k=g>>3,
// iblk = (k&1) ? 31-(2j+(k>>1)) : 2j+(k>>1) — bijective over 0..31 and every
// CU's four blocks sum to exactly 66 tiles. NO setprio (round-9 culprit).
// Everything else unchanged: K/V tiles double-buffered via global_load_lds,
// prefetch-before-compute, one barrier/tile, G4 XOR swizzle both sides,
// diet softmax (pads pre-zeroed in proj, exp2, cvt_pk), no cross-wave
// combine. 1024 blocks XCD-decoded.
// ---------------------------------------------------------------------------
__global__ __launch_bounds__(256, 2) void attn(
    const short* __restrict__ qh, const short* __restrict__ kh,
    const short* __restrict__ vhT, short* __restrict__ X) {
  // LDS shorts: [buf0: K 4096 | V 4096][buf1: K 4096 | V 4096][sP 4*1152]
  __shared__ short sm[16384 + 4 * 1152];
  const int tid = threadIdx.x, wid = tid >> 6, lane = tid & 63;
  const int quad = lane >> 4, l16 = lane & 15;
  const int xcd = blockIdx.x & 7, slot = blockIdx.x >> 3;  // 0..127
  const int bh = (xcd << 2) | (slot & 3);
  const int g = slot >> 2, jg = g & 7, kg = g >> 3;
  const int basei = 2 * jg + (kg >> 1);
  const int iblk = (kg & 1) ? (31 - basei) : basei;  // CU-balanced bijection
  const int nt = iblk + 1;            // causal extent in 64-col tiles
  const int b = bh >> 4, h = bh & 15;
  const int r0 = iblk * 64;
  const int wrow = r0 + wid * 16;  // this wave's first q-row

  const short* Q  = qh + (size_t)b * SS * DD + h * HD;
  const short* K  = kh + (size_t)b * SS * DD + h * HD;
  const short* Vt = vhT + (size_t)bh * HD * SS;
  short* sPw = &sm[16384 + wid * 1152];  // 16 rows x 72 shorts, per-wave
  const int swz = (l16 & 7) << 3;        // 16B-slot XOR swizzle, in shorts

  // staging geometry: chunk c in 0..511 covers K (row=c>>3, slot=c&7),
  // c in 512..1023 covers V likewise. Source slot pre-swizzled: slot^(row&7).
  const int sr0 = tid >> 3, ss0 = (tid & 7) ^ (sr0 & 7);          // rows 0..31
  const int sr1 = (tid + 256) >> 3, ss1 = (tid & 7) ^ (sr1 & 7);  // rows 32..63
  const short* pK0 = K + (size_t)sr0 * DD + ss0 * 8;
  const short* pK1 = K + (size_t)sr1 * DD + ss1 * 8;
  const short* pV0 = Vt + (size_t)sr0 * SS + ss0 * 8;
  const short* pV1 = Vt + (size_t)sr1 * SS + ss1 * 8;

  auto stage = [&](int buf, int t) {
    const size_t ko = (size_t)t * 64 * DD;
    const int tc = t * 64;
    short* base = &sm[buf * 8192];
    load_lds16(pK0 + ko, base + tid * 8);
    load_lds16(pK1 + ko, base + 2048 + tid * 8);
    load_lds16(pV0 + tc, base + 4096 + tid * 8);
    load_lds16(pV1 + tc, base + 6144 + tid * 8);
  };

  // Q fragments: A-layout, m = l16 (row wrow+l16), k = ks*32+quad*8
  bf16x8 aq[2];
#pragma unroll
  for (int ks = 0; ks < 2; ++ks)
    aq[ks] = *(const bf16x8*)(Q + (size_t)(wrow + l16) * DD + ks * 32 +
                              quad * 8);

  floatx4 o[4] = {};
  float lacc[4] = {};

  stage(0, 0);
  __syncthreads();
  int cur = 0;
  for (int t = 0; t < nt; ++t) {
    if (t + 1 < nt) stage(cur ^ 1, t + 1);  // prefetch next tile (no wait)
    const short* kb = &sm[cur * 8192];
    const short* vb = kb + 4096;
    // QK^T on the staged tile (swizzled reads)
    bf16x8 bk[4][2];
#pragma unroll
    for (int ni = 0; ni < 4; ++ni)
#pragma unroll
      for (int ks = 0; ks < 2; ++ks)
        bk[ni][ks] = *(const bf16x8*)&kb[(ni * 16 + l16) * 64 +
                                         ((ks * 32 + quad * 8) ^ swz)];
    floatx4 s[4] = {};
#pragma unroll
    for (int ks = 0; ks < 2; ++ks)
#pragma unroll
      for (int ni = 0; ni < 4; ++ni)
        s[ni] = __builtin_amdgcn_mfma_f32_16x16x32_bf16(aq[ks], bk[ni][ks],
                                                        s[ni], 0, 0, 0);
    const bool diag = (t == nt - 1);  // block-uniform
    const int t0 = t * 64;
#pragma unroll
    for (int ni = 0; ni < 4; ++ni)
#pragma unroll
      for (int r2p = 0; r2p < 2; ++r2p) {
        // pads pre-zeroed in proj -> s=0 -> exp2(0)=1 exactly
        float p0 = __builtin_amdgcn_exp2f(s[ni][2 * r2p]);
        float p1 = __builtin_amdgcn_exp2f(s[ni][2 * r2p + 1]);
        if (diag) {  // causal wins over pad
          const int row = wrow + quad * 4 + 2 * r2p;
          const int col = t0 + ni * 16 + l16;
          if (col > row) p0 = 0.f;
          if (col > row + 1) p1 = 0.f;
        }
        lacc[2 * r2p] += p0;
        lacc[2 * r2p + 1] += p1;
        const unsigned pk = cvtpk_bf16(p0, p1);
        short* wp = &sPw[(quad * 4 + 2 * r2p) * 72 + ni * 16 + l16];
        wp[0] = (short)pk;           // ds_write_b16
        wp[72] = (short)(pk >> 16);  // ds_write_b16_d16_hi
      }
    // O += P V : P via per-wave LDS round-trip; V from staged tile
#pragma unroll
    for (int ks = 0; ks < 2; ++ks) {
      const bf16x8 ap =
          *(const bf16x8*)&sPw[l16 * 72 + ks * 32 + quad * 8];
#pragma unroll
      for (int ei = 0; ei < 4; ++ei) {
        const bf16x8 bv = *(const bf16x8*)&vb[(ei * 16 + l16) * 64 +
                                              ((ks * 32 + quad * 8) ^ swz)];
        o[ei] = __builtin_amdgcn_mfma_f32_16x16x32_bf16(ap, bv, o[ei], 0, 0,
                                                        0);
      }
    }
    __syncthreads();  // next tile fully staged; all waves done with cur buf
    cur ^= 1;
  }

  // per-wave epilogue: denominator reduce over l16 group, scale, store
#pragma unroll
  for (int r2 = 0; r2 < 4; ++r2) {
    const float inv = 1.0f / redsum16(lacc[r2]);
    const int srow = wrow + quad * 4 + r2;
#pragma unroll
    for (int ei = 0; ei < 4; ++ei)
      X[((size_t)bh * SS + srow) * HD + ei * 16 + l16] =
          f2bf(o[ei][r2] * inv);
  }
}

// ---------------------------------------------------------------------------
// out = X[4096,1024] @ Wo, via WoT[n][k]. BM=128 BN=64 BK=32, 256 threads.
// Round-10-verified: 1D grid 512, XCD-decoded — each XCD owns 4 m-panels x
// all 16 n-blocks (X 1MB + WoT 2MB = 3MB <= 4MB L2 -> staging L2-resident
// after first touch). Round-8 XOR slot swizzle + T4 counted-vmcnt triple
// buffer (vmcnt(3) steady). UNCHANGED.
// ---------------------------------------------------------------------------
__global__ __launch_bounds__(256) void oproj(const short* __restrict__ X,
                                             const short* __restrict__ WoT,
                                             float* __restrict__ out) {
  __shared__ short sA[3][128 * 32];
  __shared__ short sB[3][64 * 32];
  const int blk = blockIdx.x;
  const int xcd = blk & 7, r = blk >> 3;          // r 0..63
  const int n0 = (r >> 2) * 64;                   // n-block 0..15 (slow)
  const int m0 = ((xcd << 2) | (r & 3)) * 128;    // m-block: XCD quad + fast
  const int tid = threadIdx.x, wid = tid >> 6, lane = tid & 63;
  const int quad = lane >> 4, l16 = lane & 15;
  const int wr = wid >> 1, wc = wid & 1;

  auto stage = [&](int buf, int kk) {
#pragma unroll
    for (int i = 0; i < 2; ++i) {
      const int c = wid * 2 + i;
      const int ci = c * 64 + lane;
      const int srow = ci >> 2;
      const int sslot = (ci & 3) ^ ((ci >> 3) & 3);
      load_lds16(X + (size_t)(m0 + srow) * DD + kk + sslot * 8,
                 &sA[buf][c * 512]);
    }
    {
      const int ci = wid * 64 + lane;
      const int srow = ci >> 2;
      const int sslot = (ci & 3) ^ ((ci >> 3) & 3);
      load_lds16(WoT + (size_t)(n0 + srow) * DD + kk + sslot * 8,
                 &sB[buf][wid * 512]);
    }
  };

  floatx4 acc[4][2] = {};
  const int qs = (quad ^ ((l16 >> 1) & 3)) * 8;  // swizzled read slot
  stage(0, 0);
  stage(1, 32);
  int b0 = 0, b1 = 1, b2 = 2;
  for (int k0 = 0; k0 < DD; k0 += 32) {
    if (k0 + 32 < DD)
      asm volatile("s_waitcnt vmcnt(3)" ::: "memory");
    else
      asm volatile("s_waitcnt vmcnt(0)" ::: "memory");
    __builtin_amdgcn_s_barrier();
    __builtin_amdgcn_sched_barrier(0);
    if (k0 + 64 < DD) stage(b2, k0 + 64);
    bf16x8 af[4], bfr[2];
#pragma unroll
    for (int mi = 0; mi < 4; ++mi)
      af[mi] = *(const bf16x8*)&sA[b0][(wr * 64 + mi * 16 + l16) * 32 + qs];
#pragma unroll
    for (int ni = 0; ni < 2; ++ni)
      bfr[ni] = *(const bf16x8*)&sB[b0][(wc * 32 + ni * 16 + l16) * 32 + qs];
#pragma unroll
    for (int mi = 0; mi < 4; ++mi)
#pragma unroll
      for (int ni = 0; ni < 2; ++ni)
        acc[mi][ni] = __builtin_amdgcn_mfma_f32_16x16x32_bf16(
            af[mi], bfr[ni], acc[mi][ni], 0, 0, 0);
    const int t = b0; b0 = b1; b1 = b2; b2 = t;
  }
#pragma unroll
  for (int mi = 0; mi < 4; ++mi)
#pragma unroll
    for (int ni = 0; ni < 2; ++ni)
#pragma unroll
      for (int r2 = 0; r2 < 4; ++r2)
        out[(size_t)(m0 + wr * 64 + mi * 16 + quad * 4 + r2) * DD + n0 +
            wc * 32 + ni * 16 + l16] = acc[mi][ni][r2];
}

// ---------------------------------------------------------------------------
extern "C" void kernel_launch(void* const* d_in, const int* in_sizes, int n_in,
                              void* d_out, int out_size, void* d_ws,
                              size_t ws_size, hipStream_t stream) {
  const float* q  = (const float*)d_in[0];
  const float* k  = (const float*)d_in[1];
  const float* v  = (const float*)d_in[2];
  const float* Wq = (const float*)d_in[3];
  const float* Wk = (const float*)d_in[4];
  const float* Wv = (const float*)d_in[5];
  const float* Wo = (const float*)d_in[6];
  const int* mask = (const int*)d_in[7];
  float* out = (float*)d_out;

  // workspace layout (shorts); X aliases qb (dead after proj). vhT has its
  // OWN region (kb is still live while proj writes vhT).
  short* ws = (short*)d_ws;
  const size_t NIN = (size_t)BB * SS * DD;  // 4,194,304
  const size_t NWH = (size_t)HH * HD * DD;  // 1,048,576
  short* qb  = ws;        // also X
  short* kb  = ws + NIN;
  short* vb  = ws + 2 * NIN;
  short* WqT = ws + 3 * NIN;
  short* WkT = WqT + NWH;
  short* WvT = WkT + NWH;
  short* WoT = WvT + NWH;
  short* qhp = WoT + (size_t)DD * DD;
  short* khp = qhp + NIN;
  short* vhT = khp + NIN;
  short* Xp  = qb;

  prep<<<dim3(7168), 256, 0, stream>>>(q, k, v, Wq, Wk, Wv, Wo, qb, kb, vb,
                                       WqT, WkT, WvT, WoT);
  proj<<<dim3(768), 256, 0, stream>>>(qb, kb, vb, WqT, WkT, WvT, mask, qhp,
                                      khp, vhT);
  attn<<<dim3(1024), 256, 0, stream>>>(qhp, khp, vhT, Xp);
  oproj<<<dim3(512), 256, 0, stream>>>(Xp, WoT, out);
}

// Round 13
// 206.415 us; speedup vs baseline: 1.0187x; 1.0187x over previous
//
#include <hip/hip_runtime.h>
#include <hip/hip_bf16.h>

#define BB 2
#define SS 2048
#define DD 1024
#define HH 16
#define HD 64

typedef __attribute__((ext_vector_type(8))) short bf16x8;
typedef __attribute__((ext_vector_type(4))) float floatx4;

__device__ __forceinline__ short f2bf(float x) {
  __hip_bfloat16 h = __float2bfloat16(x);
  return __builtin_bit_cast(short, h);
}

// pack two fp32 -> two bf16 (RNE) in one instruction
__device__ __forceinline__ unsigned cvtpk_bf16(float lo, float hi) {
  unsigned r;
  asm("v_cvt_pk_bf16_f32 %0, %1, %2" : "=v"(r) : "v"(lo), "v"(hi));
  return r;
}

// async global->LDS, 16B per lane; LDS dest is wave-uniform base + lane*16
__device__ __forceinline__ void load_lds16(const void* g, void* l) {
  __builtin_amdgcn_global_load_lds(
      (const __attribute__((address_space(1))) unsigned int*)g,
      (__attribute__((address_space(3))) unsigned int*)l, 16, 0, 0);
}

__device__ __forceinline__ float redsum16(float v) {
  v += __shfl_xor(v, 1, 64);
  v += __shfl_xor(v, 2, 64);
  v += __shfl_xor(v, 4, 64);
  v += __shfl_xor(v, 8, 64);
  return v;
}

// ---------------------------------------------------------------------------
// prep: fused conv_in (q,k,v fp32->bf16, 8 elems/thread — 2x float4 load +
// one int4 store, G13 sweet spot both sides) + conv_w (Wq/Wk/Wv transpose) +
// conv_wo (Wo transpose). 1D grid 7168, block 256.
// ---------------------------------------------------------------------------
__global__ __launch_bounds__(256) void prep(
    const float* __restrict__ q, const float* __restrict__ k,
    const float* __restrict__ v, const float* __restrict__ Wq,
    const float* __restrict__ Wk, const float* __restrict__ Wv,
    const float* __restrict__ Wo, short* __restrict__ qo,
    short* __restrict__ ko, short* __restrict__ vo, short* __restrict__ qT,
    short* __restrict__ kT, short* __restrict__ vT, short* __restrict__ WoT) {
  __shared__ short sT[64 * 72];
  const int blk = blockIdx.x;
  if (blk < 6144) {
    const int which = blk >> 11, x = blk & 2047;
    const float* src = which == 0 ? q : which == 1 ? k : v;
    short* dst       = which == 0 ? qo : which == 1 ? ko : vo;
    size_t i = ((size_t)x * 256 + threadIdx.x) * 8;
    float4 f0 = *(const float4*)(src + i);
    float4 f1 = *(const float4*)(src + i + 4);
    alignas(16) short s[8];
    s[0] = f2bf(f0.x); s[1] = f2bf(f0.y); s[2] = f2bf(f0.z);
    s[3] = f2bf(f0.w); s[4] = f2bf(f1.x); s[5] = f2bf(f1.y);
    s[6] = f2bf(f1.z); s[7] = f2bf(f1.w);
    *(int4*)(dst + i) = *(const int4*)(s);
    return;
  }
  const int t = threadIdx.x, r = t >> 2, c0 = (t & 3) * 16;
  const float* src;
  short* dst;
  if (blk < 6912) {  // conv_w: W[h][1024][64] -> WT[h*64+e][1024]
    const int b2 = blk - 6144, which = b2 >> 8, rr = b2 & 255;
    const int dtile = rr & 15, h = rr >> 4, d0 = dtile * 64;
    const float* W = which == 0 ? Wq : which == 1 ? Wk : Wv;
    short* WT      = which == 0 ? qT : which == 1 ? kT : vT;
    src = W + ((size_t)h * DD + d0 + r) * HD + c0;
    dst = WT + ((size_t)h * HD + r) * DD + d0 + c0;
  } else {  // conv_wo: Wo[1024][1024] -> WoT[n][k]
    const int b3 = blk - 6912;
    const int k0 = (b3 & 15) * 64, n0 = (b3 >> 4) * 64;
    src = Wo + (size_t)(k0 + r) * DD + n0 + c0;
    dst = WoT + (size_t)(n0 + r) * DD + k0 + c0;
  }
  const float4* s4 = (const float4*)src;
  float4 f0 = s4[0], f1 = s4[1], f2 = s4[2], f3 = s4[3];
  const float ff[16] = {f0.x, f0.y, f0.z, f0.w, f1.x, f1.y, f1.z, f1.w,
                        f2.x, f2.y, f2.z, f2.w, f3.x, f3.y, f3.z, f3.w};
#pragma unroll
  for (int j = 0; j < 16; ++j) sT[r * 72 + c0 + j] = f2bf(ff[j]);
  __syncthreads();
  alignas(16) short tmp[16];
#pragma unroll
  for (int j = 0; j < 16; ++j) tmp[j] = sT[(c0 + j) * 72 + r];
  *(int4*)(dst) = *(const int4*)(tmp);
  *(int4*)(dst + 8) = *(const int4*)(tmp + 8);
}

// ---------------------------------------------------------------------------
// Projection GEMM: ph = x @ W, M=4096, N=1024, K=1024. Round-8-verified
// (measured 40.6/40.4us twice): i-fast decode, XOR slot-swizzle both sides
// (bank-conflict-free, 3.2M->65K), T4 counted-vmcnt triple-buffer pipeline
// (vmcnt(4) steady, vmcnt(0) last; stage k+2 after barrier). UNCHANGED.
// LDS 48KB (3 bufs) + aliased v-transpose tr; grid 768 = 3 blocks/CU.
// q/k: masked rows ZEROED (score 0 -> exp2(0)=1 in attn), q scaled
// 1/8*log2(e). v: fused transpose -> vhT[bh][e][s]. XCD-decoded.
// ---------------------------------------------------------------------------
__global__ __launch_bounds__(256) void proj(
    const short* __restrict__ xq, const short* __restrict__ xk,
    const short* __restrict__ xv, const short* __restrict__ WqT,
    const short* __restrict__ WkT, const short* __restrict__ WvT,
    const int* __restrict__ mask, short* __restrict__ qh,
    short* __restrict__ kh, short* __restrict__ vhT) {
  __shared__ union {
    struct {
      short A[3][128 * 32];  // K-loop staging, triple-buffered
      short B[3][128 * 32];
    } s;
    short tr[64 * 136];  // v-transpose half-tile staging (aliases, post-loop)
  } u;
  const int xcd = blockIdx.x & 7, tt = blockIdx.x >> 3;
  const int which = tt >> 5;              // 0..2
  const int rest = tt & 31;
  const int j = ((xcd & 3) << 1) | (rest >> 4);   // n-block 0..7
  const int i = ((xcd >> 2) << 4) | (rest & 15);  // m-block 0..31 (fast)
  const short* X  = which == 0 ? xq : which == 1 ? xk : xv;
  const short* WT = which == 0 ? WqT : which == 1 ? WkT : WvT;
  const int m0 = i * 128, n0 = j * 128;
  const int tid = threadIdx.x, wid = tid >> 6, lane = tid & 63;
  const int quad = lane >> 4, l16 = lane & 15;
  const int wr = wid >> 1, wc = wid & 1;

  auto stage = [&](int buf, int kk) {
#pragma unroll
    for (int ii = 0; ii < 2; ++ii) {
      const int c = wid * 2 + ii;
      const int ci = c * 64 + lane;
      const int srow = ci >> 2;
      const int sslot = (ci & 3) ^ ((ci >> 3) & 3);  // pre-swizzled source
      load_lds16(X + (size_t)(m0 + srow) * DD + kk + sslot * 8,
                 &u.s.A[buf][c * 512]);
      load_lds16(WT + (size_t)(n0 + srow) * DD + kk + sslot * 8,
                 &u.s.B[buf][c * 512]);
    }
  };

  floatx4 acc[4][4] = {};
  const int qs = (quad ^ ((l16 >> 1) & 3)) * 8;  // swizzled read slot
  stage(0, 0);
  stage(1, 32);
  int b0 = 0, b1 = 1, b2 = 2;
  for (int k0 = 0; k0 < DD; k0 += 32) {
    if (k0 + 32 < DD)
      asm volatile("s_waitcnt vmcnt(4)" ::: "memory");
    else
      asm volatile("s_waitcnt vmcnt(0)" ::: "memory");
    __builtin_amdgcn_s_barrier();
    __builtin_amdgcn_sched_barrier(0);
    if (k0 + 64 < DD) stage(b2, k0 + 64);
    bf16x8 af[4], bfr[4];
#pragma unroll
    for (int mi = 0; mi < 4; ++mi)
      af[mi] =
          *(const bf16x8*)&u.s.A[b0][(wr * 64 + mi * 16 + l16) * 32 + qs];
#pragma unroll
    for (int ni = 0; ni < 4; ++ni)
      bfr[ni] =
          *(const bf16x8*)&u.s.B[b0][(wc * 64 + ni * 16 + l16) * 32 + qs];
#pragma unroll
    for (int mi = 0; mi < 4; ++mi)
#pragma unroll
      for (int ni = 0; ni < 4; ++ni)
        acc[mi][ni] = __builtin_amdgcn_mfma_f32_16x16x32_bf16(
            af[mi], bfr[ni], acc[mi][ni], 0, 0, 0);
    const int t = b0; b0 = b1; b1 = b2; b2 = t;  // rotate buffers
  }

  if (which != 2) {
    short* dst = which == 0 ? qh : kh;
    // q: fold 1/sqrt(64) AND log2(e) (attn uses exp2). k: unit scale.
    const float scale = (which == 0) ? 0.18033688f : 1.0f;
#pragma unroll
    for (int mi = 0; mi < 4; ++mi)
#pragma unroll
      for (int r2 = 0; r2 < 4; ++r2) {
        const int m = m0 + wr * 64 + mi * 16 + quad * 4 + r2;
        const float rs = mask[m] ? 0.f : scale;  // zero masked rows
#pragma unroll
        for (int ni = 0; ni < 4; ++ni) {
          const int n = n0 + wc * 64 + ni * 16 + l16;
          dst[(size_t)m * DD + n] = f2bf(acc[mi][ni][r2] * rs);
        }
      }
  } else {
    // v: transpose 128x128 tile -> vhT[bh][e][s], two 64-row halves through
    // u.tr (aliases staging buffers — sync: K-loop reads must all be done)
    __syncthreads();
    const int b = m0 >> 11;
#pragma unroll
    for (int p = 0; p < 2; ++p) {
      if (wc == p) {  // waves holding nl in [p*64, p*64+64)
#pragma unroll
        for (int mi = 0; mi < 4; ++mi)
#pragma unroll
          for (int ni = 0; ni < 4; ++ni)
#pragma unroll
            for (int r2 = 0; r2 < 4; ++r2) {
              const int ml = wr * 64 + mi * 16 + quad * 4 + r2;  // s-local
              const int nl = ni * 16 + l16;  // (h,e)-local within half
              u.tr[nl * 136 + ml] = f2bf(acc[mi][ni][r2]);
            }
      }
      __syncthreads();
      const int row = tid >> 2, part = tid & 3;  // row 0..63, 32-short parts
      const int gn = n0 + p * 64 + row;
      const int h = gn >> 6, e = gn & 63;
      short* dstp = vhT + ((size_t)(b * HH + h) * HD + e) * SS + (m0 & 2047) +
                    part * 32;
      const short* srcl = &u.tr[row * 136 + part * 32];
#pragma unroll
      for (int jj = 0; jj < 4; ++jj)
        *(int4*)(dstp + jj * 8) = *(const int4*)(srcl + jj * 8);
      if (p == 0) __syncthreads();
    }
  }
}

// ---------------------------------------------------------------------------
// Flash attention, cooperative-LDS version. ROUND-13: iblk decode REVERTED
// to the monotone heavy-first form `31 - (slot>>2)` — measured <=40.5us in
// rounds 8/10/11 vs 50.2us with round-12's "CU-balanced" bijection (the
// balance assumed a breadth-first workgroup->CU fill; actual fill is
// undefined and the measurement says heavy-first wins). NO setprio
// (round-9 culprit). Everything else unchanged: K/V tiles double-buffered
// via global_load_lds, prefetch-before-compute, one barrier/tile, G4 XOR
// swizzle both sides, diet softmax (pads pre-zeroed in proj, exp2, cvt_pk),
// no cross-wave combine. 1024 blocks XCD-decoded.
// ---------------------------------------------------------------------------
__global__ __launch_bounds__(256, 2) void attn(
    const short* __restrict__ qh, const short* __restrict__ kh,
    const short* __restrict__ vhT, short* __restrict__ X) {
  // LDS shorts: [buf0: K 4096 | V 4096][buf1: K 4096 | V 4096][sP 4*1152]
  __shared__ short sm[16384 + 4 * 1152];
  const int tid = threadIdx.x, wid = tid >> 6, lane = tid & 63;
  const int quad = lane >> 4, l16 = lane & 15;
  const int xcd = blockIdx.x & 7, slot = blockIdx.x >> 3;  // 0..127
  const int bh = (xcd << 2) | (slot & 3);
  const int iblk = 31 - (slot >> 2);  // heavy blocks first per XCD
  const int nt = iblk + 1;            // causal extent in 64-col tiles
  const int b = bh >> 4, h = bh & 15;
  const int r0 = iblk * 64;
  const int wrow = r0 + wid * 16;  // this wave's first q-row

  const short* Q  = qh + (size_t)b * SS * DD + h * HD;
  const short* K  = kh + (size_t)b * SS * DD + h * HD;
  const short* Vt = vhT + (size_t)bh * HD * SS;
  short* sPw = &sm[16384 + wid * 1152];  // 16 rows x 72 shorts, per-wave
  const int swz = (l16 & 7) << 3;        // 16B-slot XOR swizzle, in shorts

  // staging geometry: chunk c in 0..511 covers K (row=c>>3, slot=c&7),
  // c in 512..1023 covers V likewise. Source slot pre-swizzled: slot^(row&7).
  const int sr0 = tid >> 3, ss0 = (tid & 7) ^ (sr0 & 7);          // rows 0..31
  const int sr1 = (tid + 256) >> 3, ss1 = (tid & 7) ^ (sr1 & 7);  // rows 32..63
  const short* pK0 = K + (size_t)sr0 * DD + ss0 * 8;
  const short* pK1 = K + (size_t)sr1 * DD + ss1 * 8;
  const short* pV0 = Vt + (size_t)sr0 * SS + ss0 * 8;
  const short* pV1 = Vt + (size_t)sr1 * SS + ss1 * 8;

  auto stage = [&](int buf, int t) {
    const size_t ko = (size_t)t * 64 * DD;
    const int tc = t * 64;
    short* base = &sm[buf * 8192];
    load_lds16(pK0 + ko, base + tid * 8);
    load_lds16(pK1 + ko, base + 2048 + tid * 8);
    load_lds16(pV0 + tc, base + 4096 + tid * 8);
    load_lds16(pV1 + tc, base + 6144 + tid * 8);
  };

  // Q fragments: A-layout, m = l16 (row wrow+l16), k = ks*32+quad*8
  bf16x8 aq[2];
#pragma unroll
  for (int ks = 0; ks < 2; ++ks)
    aq[ks] = *(const bf16x8*)(Q + (size_t)(wrow + l16) * DD + ks * 32 +
                              quad * 8);

  floatx4 o[4] = {};
  float lacc[4] = {};

  stage(0, 0);
  __syncthreads();
  int cur = 0;
  for (int t = 0; t < nt; ++t) {
    if (t + 1 < nt) stage(cur ^ 1, t + 1);  // prefetch next tile (no wait)
    const short* kb = &sm[cur * 8192];
    const short* vb = kb + 4096;
    // QK^T on the staged tile (swizzled reads)
    bf16x8 bk[4][2];
#pragma unroll
    for (int ni = 0; ni < 4; ++ni)
#pragma unroll
      for (int ks = 0; ks < 2; ++ks)
        bk[ni][ks] = *(const bf16x8*)&kb[(ni * 16 + l16) * 64 +
                                         ((ks * 32 + quad * 8) ^ swz)];
    floatx4 s[4] = {};
#pragma unroll
    for (int ks = 0; ks < 2; ++ks)
#pragma unroll
      for (int ni = 0; ni < 4; ++ni)
        s[ni] = __builtin_amdgcn_mfma_f32_16x16x32_bf16(aq[ks], bk[ni][ks],
                                                        s[ni], 0, 0, 0);
    const bool diag = (t == nt - 1);  // block-uniform
    const int t0 = t * 64;
#pragma unroll
    for (int ni = 0; ni < 4; ++ni)
#pragma unroll
      for (int r2p = 0; r2p < 2; ++r2p) {
        // pads pre-zeroed in proj -> s=0 -> exp2(0)=1 exactly
        float p0 = __builtin_amdgcn_exp2f(s[ni][2 * r2p]);
        float p1 = __builtin_amdgcn_exp2f(s[ni][2 * r2p + 1]);
        if (diag) {  // causal wins over pad
          const int row = wrow + quad * 4 + 2 * r2p;
          const int col = t0 + ni * 16 + l16;
          if (col > row) p0 = 0.f;
          if (col > row + 1) p1 = 0.f;
        }
        lacc[2 * r2p] += p0;
        lacc[2 * r2p + 1] += p1;
        const unsigned pk = cvtpk_bf16(p0, p1);
        short* wp = &sPw[(quad * 4 + 2 * r2p) * 72 + ni * 16 + l16];
        wp[0] = (short)pk;           // ds_write_b16
        wp[72] = (short)(pk >> 16);  // ds_write_b16_d16_hi
      }
    // O += P V : P via per-wave LDS round-trip; V from staged tile
#pragma unroll
    for (int ks = 0; ks < 2; ++ks) {
      const bf16x8 ap =
          *(const bf16x8*)&sPw[l16 * 72 + ks * 32 + quad * 8];
#pragma unroll
      for (int ei = 0; ei < 4; ++ei) {
        const bf16x8 bv = *(const bf16x8*)&vb[(ei * 16 + l16) * 64 +
                                              ((ks * 32 + quad * 8) ^ swz)];
        o[ei] = __builtin_amdgcn_mfma_f32_16x16x32_bf16(ap, bv, o[ei], 0, 0,
                                                        0);
      }
    }
    __syncthreads();  // next tile fully staged; all waves done with cur buf
    cur ^= 1;
  }

  // per-wave epilogue: denominator reduce over l16 group, scale, store
#pragma unroll
  for (int r2 = 0; r2 < 4; ++r2) {
    const float inv = 1.0f / redsum16(lacc[r2]);
    const int srow = wrow + quad * 4 + r2;
#pragma unroll
    for (int ei = 0; ei < 4; ++ei)
      X[((size_t)bh * SS + srow) * HD + ei * 16 + l16] =
          f2bf(o[ei][r2] * inv);
  }
}

// ---------------------------------------------------------------------------
// out = X[4096,1024] @ Wo, via WoT[n][k]. BM=128 BN=64 BK=32, 256 threads.
// Round-10-verified: 1D grid 512, XCD-decoded — each XCD owns 4 m-panels x
// all 16 n-blocks (X 1MB + WoT 2MB = 3MB <= 4MB L2 -> staging L2-resident
// after first touch). Round-8 XOR slot swizzle + T4 counted-vmcnt triple
// buffer (vmcnt(3) steady). UNCHANGED.
// ---------------------------------------------------------------------------
__global__ __launch_bounds__(256) void oproj(const short* __restrict__ X,
                                             const short* __restrict__ WoT,
                                             float* __restrict__ out) {
  __shared__ short sA[3][128 * 32];
  __shared__ short sB[3][64 * 32];
  const int blk = blockIdx.x;
  const int xcd = blk & 7, r = blk >> 3;          // r 0..63
  const int n0 = (r >> 2) * 64;                   // n-block 0..15 (slow)
  const int m0 = ((xcd << 2) | (r & 3)) * 128;    // m-block: XCD quad + fast
  const int tid = threadIdx.x, wid = tid >> 6, lane = tid & 63;
  const int quad = lane >> 4, l16 = lane & 15;
  const int wr = wid >> 1, wc = wid & 1;

  auto stage = [&](int buf, int kk) {
#pragma unroll
    for (int i = 0; i < 2; ++i) {
      const int c = wid * 2 + i;
      const int ci = c * 64 + lane;
      const int srow = ci >> 2;
      const int sslot = (ci & 3) ^ ((ci >> 3) & 3);
      load_lds16(X + (size_t)(m0 + srow) * DD + kk + sslot * 8,
                 &sA[buf][c * 512]);
    }
    {
      const int ci = wid * 64 + lane;
      const int srow = ci >> 2;
      const int sslot = (ci & 3) ^ ((ci >> 3) & 3);
      load_lds16(WoT + (size_t)(n0 + srow) * DD + kk + sslot * 8,
                 &sB[buf][wid * 512]);
    }
  };

  floatx4 acc[4][2] = {};
  const int qs = (quad ^ ((l16 >> 1) & 3)) * 8;  // swizzled read slot
  stage(0, 0);
  stage(1, 32);
  int b0 = 0, b1 = 1, b2 = 2;
  for (int k0 = 0; k0 < DD; k0 += 32) {
    if (k0 + 32 < DD)
      asm volatile("s_waitcnt vmcnt(3)" ::: "memory");
    else
      asm volatile("s_waitcnt vmcnt(0)" ::: "memory");
    __builtin_amdgcn_s_barrier();
    __builtin_amdgcn_sched_barrier(0);
    if (k0 + 64 < DD) stage(b2, k0 + 64);
    bf16x8 af[4], bfr[2];
#pragma unroll
    for (int mi = 0; mi < 4; ++mi)
      af[mi] = *(const bf16x8*)&sA[b0][(wr * 64 + mi * 16 + l16) * 32 + qs];
#pragma unroll
    for (int ni = 0; ni < 2; ++ni)
      bfr[ni] = *(const bf16x8*)&sB[b0][(wc * 32 + ni * 16 + l16) * 32 + qs];
#pragma unroll
    for (int mi = 0; mi < 4; ++mi)
#pragma unroll
      for (int ni = 0; ni < 2; ++ni)
        acc[mi][ni] = __builtin_amdgcn_mfma_f32_16x16x32_bf16(
            af[mi], bfr[ni], acc[mi][ni], 0, 0, 0);
    const int t = b0; b0 = b1; b1 = b2; b2 = t;
  }
#pragma unroll
  for (int mi = 0; mi < 4; ++mi)
#pragma unroll
    for (int ni = 0; ni < 2; ++ni)
#pragma unroll
      for (int r2 = 0; r2 < 4; ++r2)
        out[(size_t)(m0 + wr * 64 + mi * 16 + quad * 4 + r2) * DD + n0 +
            wc * 32 + ni * 16 + l16] = acc[mi][ni][r2];
}

// ---------------------------------------------------------------------------
extern "C" void kernel_launch(void* const* d_in, const int* in_sizes, int n_in,
                              void* d_out, int out_size, void* d_ws,
                              size_t ws_size, hipStream_t stream) {
  const float* q  = (const float*)d_in[0];
  const float* k  = (const float*)d_in[1];
  const float* v  = (const float*)d_in[2];
  const float* Wq = (const float*)d_in[3];
  const float* Wk = (const float*)d_in[4];
  const float* Wv = (const float*)d_in[5];
  const float* Wo = (const float*)d_in[6];
  const int* mask = (const int*)d_in[7];
  float* out = (float*)d_out;

  // workspace layout (shorts); X aliases qb (dead after proj). vhT has its
  // OWN region (kb is still live while proj writes vhT).
  short* ws = (short*)d_ws;
  const size_t NIN = (size_t)BB * SS * DD;  // 4,194,304
  const size_t NWH = (size_t)HH * HD * DD;  // 1,048,576
  short* qb  = ws;        // also X
  short* kb  = ws + NIN;
  short* vb  = ws + 2 * NIN;
  short* WqT = ws + 3 * NIN;
  short* WkT = WqT + NWH;
  short* WvT = WkT + NWH;
  short* WoT = WvT + NWH;
  short* qhp = WoT + (size_t)DD * DD;
  short* khp = qhp + NIN;
  short* vhT = khp + NIN;
  short* Xp  = qb;

  prep<<<dim3(7168), 256, 0, stream>>>(q, k, v, Wq, Wk, Wv, Wo, qb, kb, vb,
                                       WqT, WkT, WvT, WoT);
  proj<<<dim3(768), 256, 0, stream>>>(qb, kb, vb, WqT, WkT, WvT, mask, qhp,
                                      khp, vhT);
  attn<<<dim3(1024), 256, 0, stream>>>(qhp, khp, vhT, Xp);
  oproj<<<dim3(512), 256, 0, stream>>>(Xp, WoT, out);
}

// Round 14
// 202.420 us; speedup vs baseline: 1.0388x; 1.0197x over previous
//
#include <hip/hip_runtime.h>
#include <hip/hip_bf16.h>

#define BB 2
#define SS 2048
#define DD 1024
#define HH 16
#define HD 64

typedef __attribute__((ext_vector_type(8))) short bf16x8;
typedef __attribute__((ext_vector_type(4))) float floatx4;

__device__ __forceinline__ short f2bf(float x) {
  __hip_bfloat16 h = __float2bfloat16(x);
  return __builtin_bit_cast(short, h);
}

// pack two fp32 -> two bf16 (RNE) in one instruction
__device__ __forceinline__ unsigned cvtpk_bf16(float lo, float hi) {
  unsigned r;
  asm("v_cvt_pk_bf16_f32 %0, %1, %2" : "=v"(r) : "v"(lo), "v"(hi));
  return r;
}

// async global->LDS, 16B per lane; LDS dest is wave-uniform base + lane*16
__device__ __forceinline__ void load_lds16(const void* g, void* l) {
  __builtin_amdgcn_global_load_lds(
      (const __attribute__((address_space(1))) unsigned int*)g,
      (__attribute__((address_space(3))) unsigned int*)l, 16, 0, 0);
}

__device__ __forceinline__ float redsum16(float v) {
  v += __shfl_xor(v, 1, 64);
  v += __shfl_xor(v, 2, 64);
  v += __shfl_xor(v, 4, 64);
  v += __shfl_xor(v, 8, 64);
  return v;
}

// ---------------------------------------------------------------------------
// prep: fused conv_in (q,k,v fp32->bf16, 8 elems/thread — 2x float4 load +
// one int4 store, G13 sweet spot both sides) + conv_w (Wq/Wk/Wv transpose) +
// conv_wo (Wo transpose). 1D grid 7168, block 256.
// ---------------------------------------------------------------------------
__global__ __launch_bounds__(256) void prep(
    const float* __restrict__ q, const float* __restrict__ k,
    const float* __restrict__ v, const float* __restrict__ Wq,
    const float* __restrict__ Wk, const float* __restrict__ Wv,
    const float* __restrict__ Wo, short* __restrict__ qo,
    short* __restrict__ ko, short* __restrict__ vo, short* __restrict__ qT,
    short* __restrict__ kT, short* __restrict__ vT, short* __restrict__ WoT) {
  __shared__ short sT[64 * 72];
  const int blk = blockIdx.x;
  if (blk < 6144) {
    const int which = blk >> 11, x = blk & 2047;
    const float* src = which == 0 ? q : which == 1 ? k : v;
    short* dst       = which == 0 ? qo : which == 1 ? ko : vo;
    size_t i = ((size_t)x * 256 + threadIdx.x) * 8;
    float4 f0 = *(const float4*)(src + i);
    float4 f1 = *(const float4*)(src + i + 4);
    alignas(16) short s[8];
    s[0] = f2bf(f0.x); s[1] = f2bf(f0.y); s[2] = f2bf(f0.z);
    s[3] = f2bf(f0.w); s[4] = f2bf(f1.x); s[5] = f2bf(f1.y);
    s[6] = f2bf(f1.z); s[7] = f2bf(f1.w);
    *(int4*)(dst + i) = *(const int4*)(s);
    return;
  }
  const int t = threadIdx.x, r = t >> 2, c0 = (t & 3) * 16;
  const float* src;
  short* dst;
  if (blk < 6912) {  // conv_w: W[h][1024][64] -> WT[h*64+e][1024]
    const int b2 = blk - 6144, which = b2 >> 8, rr = b2 & 255;
    const int dtile = rr & 15, h = rr >> 4, d0 = dtile * 64;
    const float* W = which == 0 ? Wq : which == 1 ? Wk : Wv;
    short* WT      = which == 0 ? qT : which == 1 ? kT : vT;
    src = W + ((size_t)h * DD + d0 + r) * HD + c0;
    dst = WT + ((size_t)h * HD + r) * DD + d0 + c0;
  } else {  // conv_wo: Wo[1024][1024] -> WoT[n][k]
    const int b3 = blk - 6912;
    const int k0 = (b3 & 15) * 64, n0 = (b3 >> 4) * 64;
    src = Wo + (size_t)(k0 + r) * DD + n0 + c0;
    dst = WoT + (size_t)(n0 + r) * DD + k0 + c0;
  }
  const float4* s4 = (const float4*)src;
  float4 f0 = s4[0], f1 = s4[1], f2 = s4[2], f3 = s4[3];
  const float ff[16] = {f0.x, f0.y, f0.z, f0.w, f1.x, f1.y, f1.z, f1.w,
                        f2.x, f2.y, f2.z, f2.w, f3.x, f3.y, f3.z, f3.w};
#pragma unroll
  for (int j = 0; j < 16; ++j) sT[r * 72 + c0 + j] = f2bf(ff[j]);
  __syncthreads();
  alignas(16) short tmp[16];
#pragma unroll
  for (int j = 0; j < 16; ++j) tmp[j] = sT[(c0 + j) * 72 + r];
  *(int4*)(dst) = *(const int4*)(tmp);
  *(int4*)(dst + 8) = *(const int4*)(tmp + 8);
}

// ---------------------------------------------------------------------------
// Projection GEMM: ph = x @ W, M=4096, N=1024, K=1024. Round-8-verified
// (measured 40.6/40.4/41.5us three times): i-fast decode, XOR slot-swizzle
// both sides (bank-conflict-free, 3.2M->65K), T4 counted-vmcnt triple-buffer
// pipeline (vmcnt(4) steady, vmcnt(0) last; stage k+2 after barrier).
// UNCHANGED. LDS 48KB (3 bufs) + aliased v-transpose tr; grid 768 = 3/CU.
// q/k: masked rows ZEROED (score 0 -> exp2(0)=1 in attn), q scaled
// 1/8*log2(e). v: fused transpose -> vhT[bh][e][s]. XCD-decoded.
// ---------------------------------------------------------------------------
__global__ __launch_bounds__(256) void proj(
    const short* __restrict__ xq, const short* __restrict__ xk,
    const short* __restrict__ xv, const short* __restrict__ WqT,
    const short* __restrict__ WkT, const short* __restrict__ WvT,
    const int* __restrict__ mask, short* __restrict__ qh,
    short* __restrict__ kh, short* __restrict__ vhT) {
  __shared__ union {
    struct {
      short A[3][128 * 32];  // K-loop staging, triple-buffered
      short B[3][128 * 32];
    } s;
    short tr[64 * 136];  // v-transpose half-tile staging (aliases, post-loop)
  } u;
  const int xcd = blockIdx.x & 7, tt = blockIdx.x >> 3;
  const int which = tt >> 5;              // 0..2
  const int rest = tt & 31;
  const int j = ((xcd & 3) << 1) | (rest >> 4);   // n-block 0..7
  const int i = ((xcd >> 2) << 4) | (rest & 15);  // m-block 0..31 (fast)
  const short* X  = which == 0 ? xq : which == 1 ? xk : xv;
  const short* WT = which == 0 ? WqT : which == 1 ? WkT : WvT;
  const int m0 = i * 128, n0 = j * 128;
  const int tid = threadIdx.x, wid = tid >> 6, lane = tid & 63;
  const int quad = lane >> 4, l16 = lane & 15;
  const int wr = wid >> 1, wc = wid & 1;

  auto stage = [&](int buf, int kk) {
#pragma unroll
    for (int ii = 0; ii < 2; ++ii) {
      const int c = wid * 2 + ii;
      const int ci = c * 64 + lane;
      const int srow = ci >> 2;
      const int sslot = (ci & 3) ^ ((ci >> 3) & 3);  // pre-swizzled source
      load_lds16(X + (size_t)(m0 + srow) * DD + kk + sslot * 8,
                 &u.s.A[buf][c * 512]);
      load_lds16(WT + (size_t)(n0 + srow) * DD + kk + sslot * 8,
                 &u.s.B[buf][c * 512]);
    }
  };

  floatx4 acc[4][4] = {};
  const int qs = (quad ^ ((l16 >> 1) & 3)) * 8;  // swizzled read slot
  stage(0, 0);
  stage(1, 32);
  int b0 = 0, b1 = 1, b2 = 2;
  for (int k0 = 0; k0 < DD; k0 += 32) {
    if (k0 + 32 < DD)
      asm volatile("s_waitcnt vmcnt(4)" ::: "memory");
    else
      asm volatile("s_waitcnt vmcnt(0)" ::: "memory");
    __builtin_amdgcn_s_barrier();
    __builtin_amdgcn_sched_barrier(0);
    if (k0 + 64 < DD) stage(b2, k0 + 64);
    bf16x8 af[4], bfr[4];
#pragma unroll
    for (int mi = 0; mi < 4; ++mi)
      af[mi] =
          *(const bf16x8*)&u.s.A[b0][(wr * 64 + mi * 16 + l16) * 32 + qs];
#pragma unroll
    for (int ni = 0; ni < 4; ++ni)
      bfr[ni] =
          *(const bf16x8*)&u.s.B[b0][(wc * 64 + ni * 16 + l16) * 32 + qs];
#pragma unroll
    for (int mi = 0; mi < 4; ++mi)
#pragma unroll
      for (int ni = 0; ni < 4; ++ni)
        acc[mi][ni] = __builtin_amdgcn_mfma_f32_16x16x32_bf16(
            af[mi], bfr[ni], acc[mi][ni], 0, 0, 0);
    const int t = b0; b0 = b1; b1 = b2; b2 = t;  // rotate buffers
  }

  if (which != 2) {
    short* dst = which == 0 ? qh : kh;
    // q: fold 1/sqrt(64) AND log2(e) (attn uses exp2). k: unit scale.
    const float scale = (which == 0) ? 0.18033688f : 1.0f;
#pragma unroll
    for (int mi = 0; mi < 4; ++mi)
#pragma unroll
      for (int r2 = 0; r2 < 4; ++r2) {
        const int m = m0 + wr * 64 + mi * 16 + quad * 4 + r2;
        const float rs = mask[m] ? 0.f : scale;  // zero masked rows
#pragma unroll
        for (int ni = 0; ni < 4; ++ni) {
          const int n = n0 + wc * 64 + ni * 16 + l16;
          dst[(size_t)m * DD + n] = f2bf(acc[mi][ni][r2] * rs);
        }
      }
  } else {
    // v: transpose 128x128 tile -> vhT[bh][e][s], two 64-row halves through
    // u.tr (aliases staging buffers — sync: K-loop reads must all be done)
    __syncthreads();
    const int b = m0 >> 11;
#pragma unroll
    for (int p = 0; p < 2; ++p) {
      if (wc == p) {  // waves holding nl in [p*64, p*64+64)
#pragma unroll
        for (int mi = 0; mi < 4; ++mi)
#pragma unroll
          for (int ni = 0; ni < 4; ++ni)
#pragma unroll
            for (int r2 = 0; r2 < 4; ++r2) {
              const int ml = wr * 64 + mi * 16 + quad * 4 + r2;  // s-local
              const int nl = ni * 16 + l16;  // (h,e)-local within half
              u.tr[nl * 136 + ml] = f2bf(acc[mi][ni][r2]);
            }
      }
      __syncthreads();
      const int row = tid >> 2, part = tid & 3;  // row 0..63, 32-short parts
      const int gn = n0 + p * 64 + row;
      const int h = gn >> 6, e = gn & 63;
      short* dstp = vhT + ((size_t)(b * HH + h) * HD + e) * SS + (m0 & 2047) +
                    part * 32;
      const short* srcl = &u.tr[row * 136 + part * 32];
#pragma unroll
      for (int jj = 0; jj < 4; ++jj)
        *(int4*)(dstp + jj * 8) = *(const int4*)(srcl + jj * 8);
      if (p == 0) __syncthreads();
    }
  }
}

// ---------------------------------------------------------------------------
// Flash attention, cooperative-LDS version (round-6 structure, heavy-first
// decode — measured <=40.5us 5x). ROUND-14: sP row stride 72 -> 64 shorts
// with the SAME XOR slot-swizzle as K/V (write row*64 + (col^((row&7)<<3)),
// read l16*64 + (slot^swz) — identical structure to the measured-fine kb
// reads; bijective per row). LDS drops 41984 -> 40960 B EXACTLY ->
// occupancy 3 -> 4 blocks/CU (grid is 1024 = 4/CU; was LDS-capped at 3).
// NO setprio (round-9 culprit). Everything else unchanged.
// ---------------------------------------------------------------------------
__global__ __launch_bounds__(256, 2) void attn(
    const short* __restrict__ qh, const short* __restrict__ kh,
    const short* __restrict__ vhT, short* __restrict__ X) {
  // LDS shorts: [buf0: K 4096 | V 4096][buf1: K 4096 | V 4096][sP 4*1024]
  __shared__ short sm[16384 + 4 * 1024];  // 40960 B exactly -> 4 blocks/CU
  const int tid = threadIdx.x, wid = tid >> 6, lane = tid & 63;
  const int quad = lane >> 4, l16 = lane & 15;
  const int xcd = blockIdx.x & 7, slot = blockIdx.x >> 3;  // 0..127
  const int bh = (xcd << 2) | (slot & 3);
  const int iblk = 31 - (slot >> 2);  // heavy blocks first per XCD
  const int nt = iblk + 1;            // causal extent in 64-col tiles
  const int b = bh >> 4, h = bh & 15;
  const int r0 = iblk * 64;
  const int wrow = r0 + wid * 16;  // this wave's first q-row

  const short* Q  = qh + (size_t)b * SS * DD + h * HD;
  const short* K  = kh + (size_t)b * SS * DD + h * HD;
  const short* Vt = vhT + (size_t)bh * HD * SS;
  short* sPw = &sm[16384 + wid * 1024];  // 16 rows x 64 shorts, per-wave
  const int swz = (l16 & 7) << 3;        // 16B-slot XOR swizzle, in shorts

  // staging geometry: chunk c in 0..511 covers K (row=c>>3, slot=c&7),
  // c in 512..1023 covers V likewise. Source slot pre-swizzled: slot^(row&7).
  const int sr0 = tid >> 3, ss0 = (tid & 7) ^ (sr0 & 7);          // rows 0..31
  const int sr1 = (tid + 256) >> 3, ss1 = (tid & 7) ^ (sr1 & 7);  // rows 32..63
  const short* pK0 = K + (size_t)sr0 * DD + ss0 * 8;
  const short* pK1 = K + (size_t)sr1 * DD + ss1 * 8;
  const short* pV0 = Vt + (size_t)sr0 * SS + ss0 * 8;
  const short* pV1 = Vt + (size_t)sr1 * SS + ss1 * 8;

  auto stage = [&](int buf, int t) {
    const size_t ko = (size_t)t * 64 * DD;
    const int tc = t * 64;
    short* base = &sm[buf * 8192];
    load_lds16(pK0 + ko, base + tid * 8);
    load_lds16(pK1 + ko, base + 2048 + tid * 8);
    load_lds16(pV0 + tc, base + 4096 + tid * 8);
    load_lds16(pV1 + tc, base + 6144 + tid * 8);
  };

  // Q fragments: A-layout, m = l16 (row wrow+l16), k = ks*32+quad*8
  bf16x8 aq[2];
#pragma unroll
  for (int ks = 0; ks < 2; ++ks)
    aq[ks] = *(const bf16x8*)(Q + (size_t)(wrow + l16) * DD + ks * 32 +
                              quad * 8);

  floatx4 o[4] = {};
  float lacc[4] = {};

  stage(0, 0);
  __syncthreads();
  int cur = 0;
  for (int t = 0; t < nt; ++t) {
    if (t + 1 < nt) stage(cur ^ 1, t + 1);  // prefetch next tile (no wait)
    const short* kb = &sm[cur * 8192];
    const short* vb = kb + 4096;
    // QK^T on the staged tile (swizzled reads)
    bf16x8 bk[4][2];
#pragma unroll
    for (int ni = 0; ni < 4; ++ni)
#pragma unroll
      for (int ks = 0; ks < 2; ++ks)
        bk[ni][ks] = *(const bf16x8*)&kb[(ni * 16 + l16) * 64 +
                                         ((ks * 32 + quad * 8) ^ swz)];
    floatx4 s[4] = {};
#pragma unroll
    for (int ks = 0; ks < 2; ++ks)
#pragma unroll
      for (int ni = 0; ni < 4; ++ni)
        s[ni] = __builtin_amdgcn_mfma_f32_16x16x32_bf16(aq[ks], bk[ni][ks],
                                                        s[ni], 0, 0, 0);
    const bool diag = (t == nt - 1);  // block-uniform
    const int t0 = t * 64;
#pragma unroll
    for (int ni = 0; ni < 4; ++ni)
#pragma unroll
      for (int r2p = 0; r2p < 2; ++r2p) {
        // pads pre-zeroed in proj -> s=0 -> exp2(0)=1 exactly
        float p0 = __builtin_amdgcn_exp2f(s[ni][2 * r2p]);
        float p1 = __builtin_amdgcn_exp2f(s[ni][2 * r2p + 1]);
        if (diag) {  // causal wins over pad
          const int row = wrow + quad * 4 + 2 * r2p;
          const int col = t0 + ni * 16 + l16;
          if (col > row) p0 = 0.f;
          if (col > row + 1) p1 = 0.f;
        }
        lacc[2 * r2p] += p0;
        lacc[2 * r2p + 1] += p1;
        const unsigned pk = cvtpk_bf16(p0, p1);
        // sP stride 64 + XOR swizzle (both-sides involution, rule 21):
        // row r, col c stored at r*64 + (c ^ ((r&7)<<3)); rows r (even) and
        // r+1 have different swizzle -> two separately-addressed b16 stores.
        const int prow = quad * 4 + 2 * r2p;  // even
        const int pcol = ni * 16 + l16;
        sPw[prow * 64 + (pcol ^ ((prow & 7) << 3))] = (short)pk;
        sPw[(prow + 1) * 64 + (pcol ^ (((prow + 1) & 7) << 3))] =
            (short)(pk >> 16);
      }
    // O += P V : P via per-wave LDS round-trip; V from staged tile
#pragma unroll
    for (int ks = 0; ks < 2; ++ks) {
      const bf16x8 ap =
          *(const bf16x8*)&sPw[l16 * 64 + ((ks * 32 + quad * 8) ^ swz)];
#pragma unroll
      for (int ei = 0; ei < 4; ++ei) {
        const bf16x8 bv = *(const bf16x8*)&vb[(ei * 16 + l16) * 64 +
                                              ((ks * 32 + quad * 8) ^ swz)];
        o[ei] = __builtin_amdgcn_mfma_f32_16x16x32_bf16(ap, bv, o[ei], 0, 0,
                                                        0);
      }
    }
    __syncthreads();  // next tile fully staged; all waves done with cur buf
    cur ^= 1;
  }

  // per-wave epilogue: denominator reduce over l16 group, scale, store
#pragma unroll
  for (int r2 = 0; r2 < 4; ++r2) {
    const float inv = 1.0f / redsum16(lacc[r2]);
    const int srow = wrow + quad * 4 + r2;
#pragma unroll
    for (int ei = 0; ei < 4; ++ei)
      X[((size_t)bh * SS + srow) * HD + ei * 16 + l16] =
          f2bf(o[ei][r2] * inv);
  }
}

// ---------------------------------------------------------------------------
// out = X[4096,1024] @ Wo, via WoT[n][k]. BM=128 BN=64 BK=32, 256 threads.
// Round-10-verified: 1D grid 512, XCD-decoded — each XCD owns 4 m-panels x
// all 16 n-blocks (X 1MB + WoT 2MB = 3MB <= 4MB L2 -> staging L2-resident
// after first touch). Round-8 XOR slot swizzle + T4 counted-vmcnt triple
// buffer (vmcnt(3) steady). UNCHANGED.
// ---------------------------------------------------------------------------
__global__ __launch_bounds__(256) void oproj(const short* __restrict__ X,
                                             const short* __restrict__ WoT,
                                             float* __restrict__ out) {
  __shared__ short sA[3][128 * 32];
  __shared__ short sB[3][64 * 32];
  const int blk = blockIdx.x;
  const int xcd = blk & 7, r = blk >> 3;          // r 0..63
  const int n0 = (r >> 2) * 64;                   // n-block 0..15 (slow)
  const int m0 = ((xcd << 2) | (r & 3)) * 128;    // m-block: XCD quad + fast
  const int tid = threadIdx.x, wid = tid >> 6, lane = tid & 63;
  const int quad = lane >> 4, l16 = lane & 15;
  const int wr = wid >> 1, wc = wid & 1;

  auto stage = [&](int buf, int kk) {
#pragma unroll
    for (int i = 0; i < 2; ++i) {
      const int c = wid * 2 + i;
      const int ci = c * 64 + lane;
      const int srow = ci >> 2;
      const int sslot = (ci & 3) ^ ((ci >> 3) & 3);
      load_lds16(X + (size_t)(m0 + srow) * DD + kk + sslot * 8,
                 &sA[buf][c * 512]);
    }
    {
      const int ci = wid * 64 + lane;
      const int srow = ci >> 2;
      const int sslot = (ci & 3) ^ ((ci >> 3) & 3);
      load_lds16(WoT + (size_t)(n0 + srow) * DD + kk + sslot * 8,
                 &sB[buf][wid * 512]);
    }
  };

  floatx4 acc[4][2] = {};
  const int qs = (quad ^ ((l16 >> 1) & 3)) * 8;  // swizzled read slot
  stage(0, 0);
  stage(1, 32);
  int b0 = 0, b1 = 1, b2 = 2;
  for (int k0 = 0; k0 < DD; k0 += 32) {
    if (k0 + 32 < DD)
      asm volatile("s_waitcnt vmcnt(3)" ::: "memory");
    else
      asm volatile("s_waitcnt vmcnt(0)" ::: "memory");
    __builtin_amdgcn_s_barrier();
    __builtin_amdgcn_sched_barrier(0);
    if (k0 + 64 < DD) stage(b2, k0 + 64);
    bf16x8 af[4], bfr[2];
#pragma unroll
    for (int mi = 0; mi < 4; ++mi)
      af[mi] = *(const bf16x8*)&sA[b0][(wr * 64 + mi * 16 + l16) * 32 + qs];
#pragma unroll
    for (int ni = 0; ni < 2; ++ni)
      bfr[ni] = *(const bf16x8*)&sB[b0][(wc * 32 + ni * 16 + l16) * 32 + qs];
#pragma unroll
    for (int mi = 0; mi < 4; ++mi)
#pragma unroll
      for (int ni = 0; ni < 2; ++ni)
        acc[mi][ni] = __builtin_amdgcn_mfma_f32_16x16x32_bf16(
            af[mi], bfr[ni], acc[mi][ni], 0, 0, 0);
    const int t = b0; b0 = b1; b1 = b2; b2 = t;
  }
#pragma unroll
  for (int mi = 0; mi < 4; ++mi)
#pragma unroll
    for (int ni = 0; ni < 2; ++ni)
#pragma unroll
      for (int r2 = 0; r2 < 4; ++r2)
        out[(size_t)(m0 + wr * 64 + mi * 16 + quad * 4 + r2) * DD + n0 +
            wc * 32 + ni * 16 + l16] = acc[mi][ni][r2];
}

// ---------------------------------------------------------------------------
extern "C" void kernel_launch(void* const* d_in, const int* in_sizes, int n_in,
                              void* d_out, int out_size, void* d_ws,
                              size_t ws_size, hipStream_t stream) {
  const float* q  = (const float*)d_in[0];
  const float* k  = (const float*)d_in[1];
  const float* v  = (const float*)d_in[2];
  const float* Wq = (const float*)d_in[3];
  const float* Wk = (const float*)d_in[4];
  const float* Wv = (const float*)d_in[5];
  const float* Wo = (const float*)d_in[6];
  const int* mask = (const int*)d_in[7];
  float* out = (float*)d_out;

  // workspace layout (shorts); X aliases qb (dead after proj). vhT has its
  // OWN region (kb is still live while proj writes vhT).
  short* ws = (short*)d_ws;
  const size_t NIN = (size_t)BB * SS * DD;  // 4,194,304
  const size_t NWH = (size_t)HH * HD * DD;  // 1,048,576
  short* qb  = ws;        // also X
  short* kb  = ws + NIN;
  short* vb  = ws + 2 * NIN;
  short* WqT = ws + 3 * NIN;
  short* WkT = WqT + NWH;
  short* WvT = WkT + NWH;
  short* WoT = WvT + NWH;
  short* qhp = WoT + (size_t)DD * DD;
  short* khp = qhp + NIN;
  short* vhT = khp + NIN;
  short* Xp  = qb;

  prep<<<dim3(7168), 256, 0, stream>>>(q, k, v, Wq, Wk, Wv, Wo, qb, kb, vb,
                                       WqT, WkT, WvT, WoT);
  proj<<<dim3(768), 256, 0, stream>>>(qb, kb, vb, WqT, WkT, WvT, mask, qhp,
                                      khp, vhT);
  attn<<<dim3(1024), 256, 0, stream>>>(qhp, khp, vhT, Xp);
  oproj<<<dim3(512), 256, 0, stream>>>(Xp, WoT, out);
}